// Round 8
// baseline (8747.817 us; speedup 1.0000x reference)
//
#include <hip/hip_runtime.h>

// ---------------- problem constants ----------------
#define T_SEQ 80
#define NB    5120
#define NVOC  100

// ---------------- ws layout (bytes) ----------------
#define OFF_TABLE0 0u          // 100*1024*4  = 409600
#define OFF_BIAS1  409600u     // 1024*4      = 4096
#define OFF_BP     413696u     // 786432*2    = 1572864  (granule-major B pack)
#define OFF_H1F    1986560u    // 5120*256*4  = 5242880
#define OFF_PACE   7229440u    // 4           (relaxed pacing counter)

typedef float  f32x4  __attribute__((ext_vector_type(4)));
typedef __bf16 bf16x8 __attribute__((ext_vector_type(8)));

// column permutation: n' -> original gate-major row index (i,f,g,o blocks of 256)
__device__ __host__ __forceinline__ int colmap(int np) {
  int gate = (np >> 4) & 3;
  int j    = ((np >> 6) << 4) | (np & 15);
  return gate * 256 + j;
}

__device__ __forceinline__ unsigned short f2bf(float f) {
  unsigned int u = __float_as_uint(f);
  u += 0x7fffu + ((u >> 16) & 1u);   // round-to-nearest-even
  return (unsigned short)(u >> 16);
}

__device__ __forceinline__ float sigm(float x) {
  x = fminf(fmaxf(x, -20.f), 20.f);
  return 1.f / (1.f + __expf(-x));
}
__device__ __forceinline__ float tanh_(float x) {
  x = fminf(fmaxf(x, -10.f), 10.f);
  float e = __expf(2.f * x);
  return (e - 1.f) / (e + 1.f);
}

// ---------------- prep: tables + bf16 weight repack ----------------
// Bp layout: [g:48][w:8][nf:4][lane:64][i:8] shorts.
//   granule g: L0 g<16: kc=g>>1, nh=g&1 (K=256, w_hh0)
//              L1 g>=16: kc=(g-16)>>1, nh=(g-16)&1 (K=512, [w_ih1|w_hh1])
//   np = w*128 + nh*64 + nf*16 + (lane&15);  k = kc*32 + (lane>>4)*8 + i
// elements: table0 102400 | bias1 1024 | Bp 786432 = 889856 = 3476*256
__global__ void prep_kernel(const float* __restrict__ emb,
                            const float* __restrict__ w_ih0, const float* __restrict__ w_hh0,
                            const float* __restrict__ b_ih0, const float* __restrict__ b_hh0,
                            const float* __restrict__ w_ih1, const float* __restrict__ w_hh1,
                            const float* __restrict__ b_ih1, const float* __restrict__ b_hh1,
                            float* __restrict__ table0, float* __restrict__ bias1,
                            unsigned short* __restrict__ Bp) {
  int idx = blockIdx.x * 256 + threadIdx.x;
  if (idx < 102400) {
    int v = idx >> 10, np = idx & 1023;
    int row = colmap(np);
    float s = b_ih0[row] + b_hh0[row];
#pragma unroll
    for (int e = 0; e < 8; ++e) s = fmaf(emb[v * 8 + e], w_ih0[row * 8 + e], s);
    table0[idx] = s;
  } else if (idx < 103424) {
    int np = idx - 102400;
    bias1[np] = b_ih1[colmap(np)] + b_hh1[colmap(np)];
  } else {
    int i2 = idx - 103424;            // < 786432
    int i    = i2 & 7;
    int lane = (i2 >> 3) & 63;
    int nf   = (i2 >> 9) & 3;
    int w    = (i2 >> 11) & 7;
    int g    = i2 >> 14;              // 0..47
    int np   = w * 128 + (g & 1) * 64 + nf * 16 + (lane & 15);
    int row  = colmap(np);
    float val;
    if (g < 16) {
      int k = (g >> 1) * 32 + (lane >> 4) * 8 + i;
      val = w_hh0[row * 256 + k];
    } else {
      int k = ((g - 16) >> 1) * 32 + (lane >> 4) * 8 + i;
      val = (k < 256) ? w_ih1[row * 256 + k] : w_hh1[row * 256 + (k - 256)];
    }
    Bp[i2] = f2bf(val);
  }
}

// raw barrier: LDS ops visible, vmcnt NOT drained (B register-ring keeps flowing)
__device__ __forceinline__ void bar_sync() {
  asm volatile("s_waitcnt lgkmcnt(0)" ::: "memory");
  __builtin_amdgcn_s_barrier();
}

// fence-free pacing barrier: RELAXED atomics only (no acquire/release -> no L2
// writeback/invalidate). Pure phase alignment; correctness never depends on it
// (blocks exchange no data). All 160 blocks are co-resident (160 <= 256 CUs).
__device__ __forceinline__ void pace(int* ctr, int target) {
  __syncthreads();
  if (threadIdx.x == 0) {
    __hip_atomic_fetch_add(ctr, 1, __ATOMIC_RELAXED, __HIP_MEMORY_SCOPE_AGENT);
    while (__hip_atomic_load(ctr, __ATOMIC_RELAXED, __HIP_MEMORY_SCOPE_AGENT) < target)
      __builtin_amdgcn_s_sleep(8);
  }
  __syncthreads();
}

// ---------------- persistent no-sync LSTM (R5 math, byte-identical) ----------------
// grid = 160 blocks x 512 threads (8 waves, 1 block/CU, 2 waves/SIMD).
// Block owns 32 batch rows, FULL N=1024, both layers. h0/h1 in LDS, c in VGPRs.
// B streams global(L2) -> VGPR ring (plain loads, depth-4, issue g+3 while
// consuming g) -> MFMA. Per-step relaxed pacing aligns all CUs' granule streams.
__global__ __launch_bounds__(512, 1) void lstm_nosync(
    const int* __restrict__ x,
    const float* __restrict__ table0, const float* __restrict__ bias1,
    const unsigned short* __restrict__ Bp,
    float* __restrict__ h1f, int* __restrict__ pctr) {
  __shared__ char h0t[16384];   // [32][256] bf16, XOR-swizzled
  __shared__ char h1t[16384];

  const int tid  = threadIdx.x;
  const int lane = tid & 63;
  const int wid  = tid >> 6;     // 0..7
  const int l15  = lane & 15;
  const int lhi  = lane >> 4;
  const int r0   = blockIdx.x * 32;

  const char* bpw = (const char*)Bp + (wid << 12) + (lane << 4);

  // zero h tiles
  {
    uint4 zz = {0, 0, 0, 0};
    uint4* p0 = (uint4*)h0t;
    uint4* p1 = (uint4*)h1t;
    for (int i = tid; i < 1024; i += 512) { p0[i] = zz; p1[i] = zz; }
  }

  // L1 bias per lane: bb[nh*4+gate]
  float bb[8];
#pragma unroll
  for (int nh = 0; nh < 2; ++nh)
#pragma unroll
    for (int g = 0; g < 4; ++g)
      bb[nh * 4 + g] = bias1[wid * 128 + nh * 64 + g * 16 + l15];

  int xr[8];
#pragma unroll
  for (int mr = 0; mr < 8; ++mr)
    xr[mr] = x[r0 + (mr >> 2) * 16 + lhi * 4 + (mr & 3)];

  float c0[16], c1[16];
#pragma unroll
  for (int j = 0; j < 16; ++j) { c0[j] = 0.f; c1[j] = 0.f; }

  f32x4  acc[2][2][4];   // [m][nh][gate]
  bf16x8 bring[4][4];    // register ring: [slot][nf]
  bf16x8 a0, a1;

  // load granule slice s into ring slot s&3 (plain global loads -> VGPR)
#define LOADB(s_) do { \
    const char* _g = bpw + ((s_) % 48) * 32768; \
    _Pragma("unroll") \
    for (int _nf = 0; _nf < 4; ++_nf) \
      bring[(s_) & 3][_nf] = *(const bf16x8*)(_g + _nf * 1024); \
  } while (0)

#define READ_A(tile_, m_, kc_) \
    (*(const bf16x8*)((tile_) + (((((m_) * 16 + l15) << 9) + (kc_) * 64 + (lhi << 4)) ^ ((l15 & 7) << 4))))

#define GRANULE(g_, tl_, kcL_) do { \
    if (((g_) & 1) == 0) { a0 = READ_A(tl_, 0, kcL_); a1 = READ_A(tl_, 1, kcL_); } \
    LOADB((g_) + 3); \
    _Pragma("unroll") \
    for (int _nf = 0; _nf < 4; ++_nf) { \
      acc[0][(g_) & 1][_nf] = __builtin_amdgcn_mfma_f32_16x16x32_bf16(a0, bring[(g_) & 3][_nf], acc[0][(g_) & 1][_nf], 0, 0, 0); \
      acc[1][(g_) & 1][_nf] = __builtin_amdgcn_mfma_f32_16x16x32_bf16(a1, bring[(g_) & 3][_nf], acc[1][(g_) & 1][_nf], 0, 0, 0); \
    } \
  } while (0)

  // prologue: fill 3 ring slots; __syncthreads publishes zeroed h tiles
  LOADB(0); LOADB(1); LOADB(2);
  __syncthreads();

  for (int t = 0; t < T_SEQ; ++t) {
    // fence-free phase alignment across all 160 blocks
    pace(pctr, (t + 1) * 160);

    // table gathers for this step (f32, 64B-chunk coalesced per 16-lane group)
    float tbv[8][8];
#pragma unroll
    for (int mr = 0; mr < 8; ++mr) {
      const float* tb = table0 + xr[mr] * 1024 + wid * 128 + l15;
#pragma unroll
      for (int nh = 0; nh < 2; ++nh)
#pragma unroll
        for (int g = 0; g < 4; ++g)
          tbv[mr][nh * 4 + g] = tb[nh * 64 + g * 16];
    }
    // x prefetch for next step
    {
      int tn = (t < T_SEQ - 1) ? (t + 1) : t;
#pragma unroll
      for (int mr = 0; mr < 8; ++mr)
        xr[mr] = x[tn * NB + r0 + (mr >> 2) * 16 + lhi * 4 + (mr & 3)];
    }

    // ---------- L0 GEMM: granules 0..15 (A = h0(t-1)) ----------
#pragma unroll
    for (int m = 0; m < 2; ++m)
#pragma unroll
      for (int nh = 0; nh < 2; ++nh)
#pragma unroll
        for (int nf = 0; nf < 4; ++nf) acc[m][nh][nf] = (f32x4)0.f;
#pragma unroll
    for (int g = 0; g < 16; ++g) GRANULE(g, h0t, (g >> 1));

    bar_sync();   // all waves done reading h0t(t-1)

    // ---------- epilogue L0: cell update -> h0t(t) ----------
#pragma unroll
    for (int m = 0; m < 2; ++m) {
#pragma unroll
      for (int r = 0; r < 4; ++r) {
        int row = m * 16 + lhi * 4 + r;
#pragma unroll
        for (int nh = 0; nh < 2; ++nh) {
          float gi = acc[m][nh][0][r] + tbv[m * 4 + r][nh * 4 + 0];
          float gf = acc[m][nh][1][r] + tbv[m * 4 + r][nh * 4 + 1];
          float gg = acc[m][nh][2][r] + tbv[m * 4 + r][nh * 4 + 2];
          float go = acc[m][nh][3][r] + tbv[m * 4 + r][nh * 4 + 3];
          int ci = (m * 4 + r) * 2 + nh;
          float cn = sigm(gf) * c0[ci] + sigm(gi) * tanh_(gg);
          c0[ci] = cn;
          float h = sigm(go) * tanh_(cn);
          int hc = (wid * 2 + nh) * 16 + l15;
          *(unsigned short*)(h0t + (((row << 9) + (hc << 1)) ^ ((row & 7) << 4))) = f2bf(h);
        }
      }
    }
    bar_sync();   // h0t(t) visible

    // ---------- L1 GEMM: granules 16..47 (A = [h0(t) | h1(t-1)]) ----------
#pragma unroll
    for (int m = 0; m < 2; ++m)
#pragma unroll
      for (int nh = 0; nh < 2; ++nh)
#pragma unroll
        for (int nf = 0; nf < 4; ++nf) acc[m][nh][nf] = (f32x4)0.f;
#pragma unroll
    for (int g = 16; g < 48; ++g) {
      const int kc = (g - 16) >> 1;
      const char* tl = (kc < 8) ? h0t : h1t;
      GRANULE(g, tl, (kc & 7));
    }
    bar_sync();   // all waves done reading h1t(t-1)

    // ---------- epilogue L1: cell update -> h1t(t) (+ h1f at t=79) ----------
#pragma unroll
    for (int m = 0; m < 2; ++m) {
#pragma unroll
      for (int r = 0; r < 4; ++r) {
        int row = m * 16 + lhi * 4 + r;
#pragma unroll
        for (int nh = 0; nh < 2; ++nh) {
          float gi = acc[m][nh][0][r] + bb[nh * 4 + 0];
          float gf = acc[m][nh][1][r] + bb[nh * 4 + 1];
          float gg = acc[m][nh][2][r] + bb[nh * 4 + 2];
          float go = acc[m][nh][3][r] + bb[nh * 4 + 3];
          int ci = (m * 4 + r) * 2 + nh;
          float cn = sigm(gf) * c1[ci] + sigm(gi) * tanh_(gg);
          c1[ci] = cn;
          float h = sigm(go) * tanh_(cn);
          int hc = (wid * 2 + nh) * 16 + l15;
          *(unsigned short*)(h1t + (((row << 9) + (hc << 1)) ^ ((row & 7) << 4))) = f2bf(h);
          if (t == T_SEQ - 1) h1f[(size_t)(r0 + row) * 256 + hc] = h;
        }
      }
    }
    // no 4th barrier: next step's bar#1/#2 order epi1 writes before their readers
  }
#undef LOADB
#undef READ_A
#undef GRANULE
}

// ---------------- decoder: out[64][100] = flat[64][20480] @ dec_w^T + dec_b ----------------
__global__ void decoder_kernel(const float* __restrict__ h1f,
                               const float* __restrict__ dec_w,
                               const float* __restrict__ dec_b,
                               float* __restrict__ out) {
  __shared__ float red[256];
  const int tid = threadIdx.x, lane = tid & 63, wid = tid >> 6;
  const int v = blockIdx.x;
  float dacc[64];
#pragma unroll
  for (int r = 0; r < 64; ++r) dacc[r] = 0.f;
  for (int q = tid; q < 20480; q += 256) {
    float w = dec_w[(size_t)v * 20480 + q];
    const float* fp = h1f + q;
#pragma unroll
    for (int r = 0; r < 64; ++r) dacc[r] = fmaf(fp[r * 20480], w, dacc[r]);
  }
#pragma unroll
  for (int r = 0; r < 64; ++r) {
    float s = dacc[r];
    for (int off = 32; off > 0; off >>= 1) s += __shfl_down(s, off, 64);
    if (lane == 0) red[wid * 64 + r] = s;
  }
  __syncthreads();
  if (tid < 64) {
    float s = red[tid] + red[64 + tid] + red[128 + tid] + red[192 + tid];
    out[tid * 100 + v] = s + dec_b[v];
  }
}

// ---------------- host launch ----------------
extern "C" void kernel_launch(void* const* d_in, const int* in_sizes, int n_in,
                              void* d_out, int out_size, void* d_ws, size_t ws_size,
                              hipStream_t stream) {
  const int*   x     = (const int*)d_in[0];
  const float* emb   = (const float*)d_in[1];
  const float* w_ih0 = (const float*)d_in[2];
  const float* w_hh0 = (const float*)d_in[3];
  const float* b_ih0 = (const float*)d_in[4];
  const float* b_hh0 = (const float*)d_in[5];
  const float* w_ih1 = (const float*)d_in[6];
  const float* w_hh1 = (const float*)d_in[7];
  const float* b_ih1 = (const float*)d_in[8];
  const float* b_hh1 = (const float*)d_in[9];
  const float* dec_w = (const float*)d_in[10];
  const float* dec_b = (const float*)d_in[11];
  float* out = (float*)d_out;
  char* ws = (char*)d_ws;

  float*          table0 = (float*)(ws + OFF_TABLE0);
  float*          bias1  = (float*)(ws + OFF_BIAS1);
  unsigned short* Bp     = (unsigned short*)(ws + OFF_BP);
  float*          h1f    = (float*)(ws + OFF_H1F);
  int*            pctr   = (int*)(ws + OFF_PACE);

  hipMemsetAsync(pctr, 0, 4, stream);
  prep_kernel<<<3476, 256, 0, stream>>>(emb, w_ih0, w_hh0, b_ih0, b_hh0,
                                        w_ih1, w_hh1, b_ih1, b_hh1,
                                        table0, bias1, Bp);
  lstm_nosync<<<160, 512, 0, stream>>>(x, table0, bias1, Bp, h1f, pctr);
  decoder_kernel<<<NVOC, 256, 0, stream>>>(h1f, dec_w, dec_b, out);
}

// Round 9
// 3185.084 us; speedup vs baseline: 2.7465x; 2.7465x over previous
//
#include <hip/hip_runtime.h>

// ---------------- problem constants ----------------
#define T_SEQ 80
#define NB    5120
#define NBH   (NB * 256)
#define NVOC  100

// ---------------- ws layout (bytes), total 16,142,336 ----------------
#define OFF_TABLE0 0u          // 100*1024*4 = 409600 (f32, np-packed)
#define OFF_BIAS1  409600u     // 1024*4     = 4096
#define OFF_RING0  413696u     // 2 slots bf16 [5120][256] = 5242880
#define OFF_RING1  5656576u    // 2 slots bf16             = 5242880
#define OFF_C0     10899456u   // _Float16 [5120][256]     = 2621440
#define OFF_C1     13520896u   // _Float16 [5120][256]     = 2621440

// LDS: Abuf 2x(320 rows x 80B) = 51200 + Bbuf 2x(8x64x8 bf16) = 16384
#define SMEM_BYTES 67584

typedef float  f32x4  __attribute__((ext_vector_type(4)));
typedef __bf16 bf16x8 __attribute__((ext_vector_type(8)));
typedef short  s16x8  __attribute__((ext_vector_type(8)));

// column permutation: np -> original gate-major row (i,f,g,o blocks of 256)
__device__ __forceinline__ int colmap(int np) {
  int gate = (np >> 4) & 3;
  int j    = ((np >> 6) << 4) | (np & 15);
  return gate * 256 + j;
}

__device__ __forceinline__ unsigned short f2bf(float f) {
  unsigned int u = __float_as_uint(f);
  u += 0x7fffu + ((u >> 16) & 1u);   // RNE
  return (unsigned short)(u >> 16);
}
__device__ __forceinline__ float bf2f(unsigned short s) {
  return __uint_as_float(((unsigned int)s) << 16);
}
__device__ __forceinline__ float sigm(float x) {
  x = fminf(fmaxf(x, -20.f), 20.f);
  return 1.f / (1.f + __expf(-x));
}
__device__ __forceinline__ float tanh_(float x) {
  x = fminf(fmaxf(x, -10.f), 10.f);
  float e = __expf(2.f * x);
  return (e - 1.f) / (e + 1.f);
}

// ---------------- prep: x-projection table (f32 exact) + fused L1 bias ----------------
__global__ void prep_kernel(const float* __restrict__ emb,
                            const float* __restrict__ w_ih0,
                            const float* __restrict__ b_ih0, const float* __restrict__ b_hh0,
                            const float* __restrict__ b_ih1, const float* __restrict__ b_hh1,
                            float* __restrict__ table0, float* __restrict__ bias1) {
  int idx = blockIdx.x * 256 + threadIdx.x;
  if (idx < 102400) {
    int v = idx >> 10, np = idx & 1023;
    int row = colmap(np);
    float s = b_ih0[row] + b_hh0[row];
#pragma unroll
    for (int e = 0; e < 8; ++e) s = fmaf(emb[v * 8 + e], w_ih0[row * 8 + e], s);
    table0[idx] = s;
  } else if (idx < 103424) {
    int np = idx - 102400;
    bias1[np] = b_ih1[colmap(np)] + b_hh1[colmap(np)];
  }
}

// ---------------- per-step kernel: L0(t=s) on blocks 0..127, L1(t=s-1) on 128..255 ----
// Tile [320 rows x 128 gate-cols], 512 thr = 8 waves (4m x 2n), wave [80 x 64].
// A (h-state, bf16 ring) + B (f32 d_in weights, cvt->bf16) staged to LDS,
// double-buffered, loads issued early / LDS-writes late (latency hides under MFMA).
__global__ __launch_bounds__(512, 1) void step_kernel(
    int s, const int* __restrict__ x,
    const float* __restrict__ table0, const float* __restrict__ bias1,
    const float* __restrict__ w_hh0, const float* __restrict__ w_ih1,
    const float* __restrict__ w_hh1,
    unsigned short* __restrict__ ring0, unsigned short* __restrict__ ring1,
    _Float16* __restrict__ c0h, _Float16* __restrict__ c1h) {
  extern __shared__ char smem[];
  char* Ab = smem;            // [2][320*80]
  char* Bb = smem + 51200;    // [2][512*16]

  const int tid = threadIdx.x;
  const int lane = tid & 63, wid = tid >> 6;
  const int l15 = lane & 15, lhi = lane >> 4;
  const int wm = wid >> 1, wn = wid & 1, rw = wm * 80;
  const bool isL0 = blockIdx.x < 128;
  const int bb = blockIdx.x & 127;
  const int mi = bb >> 3, ni = bb & 7;
  const int rows = mi * 320;

  int t;
  if (isL0) { if (s == T_SEQ) return; t = s; }
  else      { if (s == 0)     return; t = s - 1; }

  const unsigned short* ring0Prev = ring0 + ((s + 1) & 1) * NBH;  // h0(s-1)
  unsigned short*       ring0Cur  = ring0 + (s & 1) * NBH;        // h0(s)
  const unsigned short* h1Prev    = ring1 + (s & 1) * NBH;        // h1(s-2)
  unsigned short*       h1Cur     = ring1 + ((s + 1) & 1) * NBH;  // h1(s-1)

  const int KC = isL0 ? (t > 0 ? 8 : 0) : (t > 0 ? 16 : 8);

  // per-thread B-stage address: pack target Bb[nfb=tid>>6][ln=tid&63][8]
  const int lnp = tid & 63;
  const int browBase = colmap(ni * 128 + (tid >> 6) * 16 + (lnp & 15)) * 256 + ((lnp >> 4) << 3);

  f32x4 acc[5][4];
#pragma unroll
  for (int m = 0; m < 5; ++m)
#pragma unroll
    for (int nf = 0; nf < 4; ++nf) acc[m][nf] = (f32x4)0.f;

  uint4 au0, au1, au2;
  f32x4 bu0, bu1;

#define LOADR(kc_) do { \
    const unsigned short* _As; int _ko; \
    if (isL0) { _As = ring0Prev; _ko = (kc_) * 32; } \
    else { _As = ((kc_) < 8) ? ring0Prev : h1Prev; _ko = ((kc_) & 7) * 32; } \
    { int _c = tid;        au0 = *(const uint4*)(_As + (rows + (_c >> 2)) * 256 + _ko + ((_c & 3) << 3)); } \
    { int _c = tid + 512;  au1 = *(const uint4*)(_As + (rows + (_c >> 2)) * 256 + _ko + ((_c & 3) << 3)); } \
    if (tid < 256) { int _c = tid + 1024; au2 = *(const uint4*)(_As + (rows + (_c >> 2)) * 256 + _ko + ((_c & 3) << 3)); } \
    const float* _W; int _kb; \
    if (isL0) { _W = w_hh0; _kb = (kc_) * 32; } \
    else if ((kc_) < 8) { _W = w_ih1; _kb = (kc_) * 32; } \
    else { _W = w_hh1; _kb = ((kc_) - 8) * 32; } \
    bu0 = *(const f32x4*)(_W + browBase + _kb); \
    bu1 = *(const f32x4*)(_W + browBase + _kb + 4); \
  } while (0)

#define STORER(buf_) do { \
    char* _ab = Ab + (buf_) * 25600; \
    *(uint4*)(_ab + (tid >> 2) * 80 + (tid & 3) * 16) = au0; \
    { int _c = tid + 512; *(uint4*)(_ab + (_c >> 2) * 80 + (_c & 3) * 16) = au1; } \
    if (tid < 256) { int _c = tid + 1024; *(uint4*)(_ab + (_c >> 2) * 80 + (_c & 3) * 16) = au2; } \
    s16x8 _bs; \
    _Pragma("unroll") \
    for (int _e = 0; _e < 4; ++_e) { \
      _bs[_e]     = (short)f2bf(bu0[_e]); \
      _bs[_e + 4] = (short)f2bf(bu1[_e]); \
    } \
    *(s16x8*)(Bb + (buf_) * 8192 + tid * 16) = _bs; \
  } while (0)

#define CONSUME(buf_) do { \
    const char* _ab = Ab + (buf_) * 25600; \
    const char* _bp = Bb + (buf_) * 8192; \
    bf16x8 _bld[4]; \
    _Pragma("unroll") \
    for (int _nf = 0; _nf < 4; ++_nf) \
      _bld[_nf] = *(const bf16x8*)(_bp + ((wn * 4 + _nf) * 64 + lane) * 16); \
    _Pragma("unroll") \
    for (int _m = 0; _m < 5; ++_m) { \
      bf16x8 _a = *(const bf16x8*)(_ab + (rw + _m * 16 + l15) * 80 + lhi * 16); \
      _Pragma("unroll") \
      for (int _nf = 0; _nf < 4; ++_nf) \
        acc[_m][_nf] = __builtin_amdgcn_mfma_f32_16x16x32_bf16(_a, _bld[_nf], acc[_m][_nf], 0, 0, 0); \
    } \
  } while (0)

  if (KC > 0) { LOADR(0); STORER(0); }
#pragma unroll 1
  for (int kc = 0; kc < KC; ++kc) {
    __syncthreads();                       // publishes buf[kc&1]
    const bool more = (kc + 1 < KC);
    if (more) LOADR(kc + 1);               // issue early: hides under MFMAs
    CONSUME(kc & 1);
    if (more) STORER((kc + 1) & 1);        // write late (safe: readers of this
  }                                        // parity synced at loop top)

  // ---------------- epilogue: LSTM cell update ----------------
  const int jh  = (ni * 2 + wn) * 16 + l15;        // h-column
  if (isL0) {
    const int tbb = ni * 128 + wn * 64 + l15;
#pragma unroll
    for (int m = 0; m < 5; ++m) {
#pragma unroll
      for (int r = 0; r < 4; ++r) {
        int rowg = rows + rw + m * 16 + lhi * 4 + r;
        int v = x[t * NB + rowg];
        const float* tb = table0 + v * 1024 + tbb;
        float gi = acc[m][0][r] + tb[0];
        float gf = acc[m][1][r] + tb[16];
        float gg = acc[m][2][r] + tb[32];
        float go = acc[m][3][r] + tb[48];
        float cold = (t > 0) ? (float)c0h[rowg * 256 + jh] : 0.f;
        float cn = sigm(gf) * cold + sigm(gi) * tanh_(gg);
        c0h[rowg * 256 + jh] = (_Float16)cn;
        ring0Cur[rowg * 256 + jh] = f2bf(sigm(go) * tanh_(cn));
      }
    }
  } else {
    const int bbb = ni * 128 + wn * 64 + l15;
    float b0 = bias1[bbb], b1 = bias1[bbb + 16], b2 = bias1[bbb + 32], b3 = bias1[bbb + 48];
#pragma unroll
    for (int m = 0; m < 5; ++m) {
#pragma unroll
      for (int r = 0; r < 4; ++r) {
        int rowg = rows + rw + m * 16 + lhi * 4 + r;
        float gi = acc[m][0][r] + b0;
        float gf = acc[m][1][r] + b1;
        float gg = acc[m][2][r] + b2;
        float go = acc[m][3][r] + b3;
        float cold = (t > 0) ? (float)c1h[rowg * 256 + jh] : 0.f;
        float cn = sigm(gf) * cold + sigm(gi) * tanh_(gg);
        c1h[rowg * 256 + jh] = (_Float16)cn;
        h1Cur[rowg * 256 + jh] = f2bf(sigm(go) * tanh_(cn));
      }
    }
  }
#undef LOADR
#undef STORER
#undef CONSUME
}

// ---------------- decoder: out[64][100] from bf16 h1(79) ring slot 1 ----------------
__global__ void decoder_kernel(const unsigned short* __restrict__ h1,
                               const float* __restrict__ dec_w,
                               const float* __restrict__ dec_b,
                               float* __restrict__ out) {
  __shared__ float red[256];
  const int tid = threadIdx.x, lane = tid & 63, wid = tid >> 6;
  const int v = blockIdx.x;
  float dacc[64];
#pragma unroll
  for (int r = 0; r < 64; ++r) dacc[r] = 0.f;
  for (int q = tid; q < 20480; q += 256) {
    float w = dec_w[(size_t)v * 20480 + q];
    const unsigned short* fp = h1 + q;
#pragma unroll
    for (int r = 0; r < 64; ++r) dacc[r] = fmaf(bf2f(fp[r * 20480]), w, dacc[r]);
  }
#pragma unroll
  for (int r = 0; r < 64; ++r) {
    float s = dacc[r];
    for (int off = 32; off > 0; off >>= 1) s += __shfl_down(s, off, 64);
    if (lane == 0) red[wid * 64 + r] = s;
  }
  __syncthreads();
  if (tid < 64) {
    float s = red[tid] + red[64 + tid] + red[128 + tid] + red[192 + tid];
    out[tid * 100 + v] = s + dec_b[v];
  }
}

// ---------------- host launch: prep + 81 step kernels + decoder ----------------
extern "C" void kernel_launch(void* const* d_in, const int* in_sizes, int n_in,
                              void* d_out, int out_size, void* d_ws, size_t ws_size,
                              hipStream_t stream) {
  const int*   x     = (const int*)d_in[0];
  const float* emb   = (const float*)d_in[1];
  const float* w_ih0 = (const float*)d_in[2];
  const float* w_hh0 = (const float*)d_in[3];
  const float* b_ih0 = (const float*)d_in[4];
  const float* b_hh0 = (const float*)d_in[5];
  const float* w_ih1 = (const float*)d_in[6];
  const float* w_hh1 = (const float*)d_in[7];
  const float* b_ih1 = (const float*)d_in[8];
  const float* b_hh1 = (const float*)d_in[9];
  const float* dec_w = (const float*)d_in[10];
  const float* dec_b = (const float*)d_in[11];
  float* out = (float*)d_out;
  char* ws = (char*)d_ws;

  float*          table0 = (float*)(ws + OFF_TABLE0);
  float*          bias1  = (float*)(ws + OFF_BIAS1);
  unsigned short* ring0  = (unsigned short*)(ws + OFF_RING0);
  unsigned short* ring1  = (unsigned short*)(ws + OFF_RING1);
  _Float16*       c0h    = (_Float16*)(ws + OFF_C0);
  _Float16*       c1h    = (_Float16*)(ws + OFF_C1);

  prep_kernel<<<404, 256, 0, stream>>>(emb, w_ih0, b_ih0, b_hh0, b_ih1, b_hh1,
                                       table0, bias1);
  hipFuncSetAttribute((const void*)step_kernel,
                      hipFuncAttributeMaxDynamicSharedMemorySize, SMEM_BYTES);
  for (int s = 0; s <= T_SEQ; ++s)
    step_kernel<<<256, 512, SMEM_BYTES, stream>>>(s, x, table0, bias1,
                                                  w_hh0, w_ih1, w_hh1,
                                                  ring0, ring1, c0h, c1h);
  decoder_kernel<<<NVOC, 256, 0, stream>>>(ring1 + NBH, dec_w, dec_b, out);
}

// Round 10
// 2123.337 us; speedup vs baseline: 4.1198x; 1.5000x over previous
//
#include <hip/hip_runtime.h>

// ---------------- problem constants ----------------
#define T_SEQ 80
#define NB    5120
#define NBH   (NB * 256)
#define NVOC  100

// ---------------- ws layout (bytes), total ~17.7 MB ----------------
#define OFF_TABLE0 0u          // 100*1024*4 = 409600 (f32, np-packed)
#define OFF_BIAS1  409600u     // 1024*4     = 4096
#define OFF_BPACK  413696u     // 786432*2   = 1572864 (bf16 frag-layout weights)
#define OFF_RING0  1986560u    // 2 slots bf16 [5120][256] = 5242880
#define OFF_RING1  7229440u    // 2 slots bf16             = 5242880
#define OFF_C0     12472320u   // _Float16 [5120][256]     = 2621440
#define OFF_C1     15093760u   // _Float16 [5120][256]     = 2621440

// LDS: Abuf 2x(320 rows x 80B) = 51200 + Bbuf 2x(512x16B) = 16384
#define SMEM_BYTES 67584

typedef float  f32x4  __attribute__((ext_vector_type(4)));
typedef __bf16 bf16x8 __attribute__((ext_vector_type(8)));
typedef short  s16x8  __attribute__((ext_vector_type(8)));
typedef unsigned short u16x4 __attribute__((ext_vector_type(4)));

// column permutation: np -> original gate-major row (i,f,g,o blocks of 256)
__device__ __forceinline__ int colmap(int np) {
  int gate = (np >> 4) & 3;
  int j    = ((np >> 6) << 4) | (np & 15);
  return gate * 256 + j;
}

__device__ __forceinline__ unsigned short f2bf(float f) {
  unsigned int u = __float_as_uint(f);
  u += 0x7fffu + ((u >> 16) & 1u);   // RNE
  return (unsigned short)(u >> 16);
}
__device__ __forceinline__ float bf2f(unsigned short s) {
  return __uint_as_float(((unsigned int)s) << 16);
}
__device__ __forceinline__ float sigm(float x) {
  x = fminf(fmaxf(x, -20.f), 20.f);
  return 1.f / (1.f + __expf(-x));
}
__device__ __forceinline__ float tanh_(float x) {
  x = fminf(fmaxf(x, -10.f), 10.f);
  float e = __expf(2.f * x);
  return (e - 1.f) / (e + 1.f);
}

// ---------------- prep: table + bias + bf16 weight pack ----------------
// Bpack layout: [slot:24][ni:8][t:512][i:8] shorts; slot<8: L0 kc=slot (w_hh0);
// slot>=8: L1 kc=slot-8 (kc<8: w_ih1, else w_hh1). Matches step LDS Bb layout:
//   np = ni*128 + (t>>6)*16 + (t&15); k = kbase + ((t&63)>>4)*8 + i.
// elements: 102400 + 1024 + 786432 = 889856 = 3476*256
__global__ void prep_kernel(const float* __restrict__ emb,
                            const float* __restrict__ w_ih0, const float* __restrict__ w_hh0,
                            const float* __restrict__ b_ih0, const float* __restrict__ b_hh0,
                            const float* __restrict__ w_ih1, const float* __restrict__ w_hh1,
                            const float* __restrict__ b_ih1, const float* __restrict__ b_hh1,
                            float* __restrict__ table0, float* __restrict__ bias1,
                            unsigned short* __restrict__ Bpack) {
  int idx = blockIdx.x * 256 + threadIdx.x;
  if (idx < 102400) {
    int v = idx >> 10, np = idx & 1023;
    int row = colmap(np);
    float s = b_ih0[row] + b_hh0[row];
#pragma unroll
    for (int e = 0; e < 8; ++e) s = fmaf(emb[v * 8 + e], w_ih0[row * 8 + e], s);
    table0[idx] = s;
  } else if (idx < 103424) {
    int np = idx - 102400;
    bias1[np] = b_ih1[colmap(np)] + b_hh1[colmap(np)];
  } else {
    int i2 = idx - 103424;               // < 786432
    int i    = i2 & 7;
    int t    = (i2 >> 3) & 511;
    int ni   = (i2 >> 12) & 7;
    int slot = i2 >> 15;                 // 0..23
    int np   = ni * 128 + ((t >> 6) << 4) + (t & 15);
    int row  = colmap(np);
    int k    = (((t & 63) >> 4) << 3) + i;
    float val;
    if (slot < 8) {
      val = w_hh0[row * 256 + slot * 32 + k];
    } else {
      int kc = slot - 8;
      const float* W = (kc < 8) ? w_ih1 : w_hh1;
      val = W[row * 256 + (kc & 7) * 32 + k];
    }
    Bpack[i2] = f2bf(val);
  }
}

// ---------------- per-step kernel ----------------
// XCD-aware: p -> (xcd=p&7, idx=p>>3). idx<16: L0(t=s), else L1(t=s-1).
// Each XCD owns 2 full mi-groups per layer (all 8 ni together) -> A-tile lines
// fetched once chip-wide. Tile [320 x 128], 8 waves (4m x 2n), wave [80 x 64].
__global__ __launch_bounds__(512, 1) void step_kernel(
    int s, const int* __restrict__ x,
    const float* __restrict__ table0, const float* __restrict__ bias1,
    const unsigned short* __restrict__ Bpack,
    unsigned short* __restrict__ ring0, unsigned short* __restrict__ ring1,
    _Float16* __restrict__ c0h, _Float16* __restrict__ c1h) {
  extern __shared__ char smem[];
  char* Ab = smem;            // [2][320*80]
  char* Bb = smem + 51200;    // [2][512*16]

  const int tid = threadIdx.x;
  const int lane = tid & 63, wid = tid >> 6;
  const int l15 = lane & 15, lhi = lane >> 4;
  const int wm = wid >> 1, wn = wid & 1, rw = wm * 80;

  const int p = blockIdx.x;
  const int xcd = p & 7, idx = p >> 3;
  const bool isL0 = idx < 16;
  const int sub = isL0 ? idx : (idx - 16);
  const int mi = xcd * 2 + (sub >> 3);
  const int ni = sub & 7;
  const int rows = mi * 320;

  int t;
  if (isL0) { if (s == T_SEQ) return; t = s; }
  else      { if (s == 0)     return; t = s - 1; }

  const unsigned short* ring0Prev = ring0 + ((s + 1) & 1) * NBH;  // h0(s-1)
  unsigned short*       ring0Cur  = ring0 + (s & 1) * NBH;        // h0(s)
  const unsigned short* h1Prev    = ring1 + (s & 1) * NBH;        // h1(s-2)
  unsigned short*       h1Cur     = ring1 + ((s + 1) & 1) * NBH;  // h1(s-1)

  const int KC = isL0 ? (t > 0 ? 8 : 0) : (t > 0 ? 16 : 8);

  f32x4 acc[5][4];
#pragma unroll
  for (int m = 0; m < 5; ++m)
#pragma unroll
    for (int nf = 0; nf < 4; ++nf) acc[m][nf] = (f32x4)0.f;

  uint4 au0, au1, au2;
  s16x8 bsr;

#define LOADR(kc_) do { \
    const unsigned short* _As; int _ko; \
    if (isL0) { _As = ring0Prev; _ko = (kc_) * 32; } \
    else { _As = ((kc_) < 8) ? ring0Prev : h1Prev; _ko = ((kc_) & 7) * 32; } \
    { int _c = tid;        au0 = *(const uint4*)(_As + (rows + (_c >> 2)) * 256 + _ko + ((_c & 3) << 3)); } \
    { int _c = tid + 512;  au1 = *(const uint4*)(_As + (rows + (_c >> 2)) * 256 + _ko + ((_c & 3) << 3)); } \
    if (tid < 256) { int _c = tid + 1024; au2 = *(const uint4*)(_As + (rows + (_c >> 2)) * 256 + _ko + ((_c & 3) << 3)); } \
    int _slot = isL0 ? (kc_) : (8 + (kc_)); \
    bsr = *(const s16x8*)(Bpack + (((_slot * 8 + ni) * 512 + tid) << 3)); \
  } while (0)

#define STORER(buf_) do { \
    char* _ab = Ab + (buf_) * 25600; \
    *(uint4*)(_ab + (tid >> 2) * 80 + (tid & 3) * 16) = au0; \
    { int _c = tid + 512; *(uint4*)(_ab + (_c >> 2) * 80 + (_c & 3) * 16) = au1; } \
    if (tid < 256) { int _c = tid + 1024; *(uint4*)(_ab + (_c >> 2) * 80 + (_c & 3) * 16) = au2; } \
    *(s16x8*)(Bb + (buf_) * 8192 + tid * 16) = bsr; \
  } while (0)

#define CONSUME(buf_) do { \
    const char* _ab = Ab + (buf_) * 25600; \
    const char* _bp = Bb + (buf_) * 8192; \
    bf16x8 _bld[4]; \
    _Pragma("unroll") \
    for (int _nf = 0; _nf < 4; ++_nf) \
      _bld[_nf] = *(const bf16x8*)(_bp + ((wn * 4 + _nf) * 64 + lane) * 16); \
    _Pragma("unroll") \
    for (int _m = 0; _m < 5; ++_m) { \
      bf16x8 _a = *(const bf16x8*)(_ab + (rw + _m * 16 + l15) * 80 + lhi * 16); \
      _Pragma("unroll") \
      for (int _nf = 0; _nf < 4; ++_nf) \
        acc[_m][_nf] = __builtin_amdgcn_mfma_f32_16x16x32_bf16(_a, _bld[_nf], acc[_m][_nf], 0, 0, 0); \
    } \
  } while (0)

  if (KC > 0) { LOADR(0); STORER(0); }
#pragma unroll 1
  for (int kc = 0; kc < KC; ++kc) {
    __syncthreads();                       // publishes buf[kc&1]
    const bool more = (kc + 1 < KC);
    if (more) LOADR(kc + 1);               // issue early: hides under MFMAs
    CONSUME(kc & 1);
    if (more) STORER((kc + 1) & 1);        // write late (readers synced at top)
  }

  // ---------------- epilogue: LSTM cell update ----------------
  const int jh = (ni * 2 + wn) * 16 + l15;         // h-column
  if (isL0) {
    const int tbb = ni * 128 + wn * 64 + l15;
#pragma unroll
    for (int m = 0; m < 5; ++m) {
#pragma unroll
      for (int r = 0; r < 4; ++r) {
        int rowg = rows + rw + m * 16 + lhi * 4 + r;
        int v = x[t * NB + rowg];
        const float* tb = table0 + v * 1024 + tbb;
        float gi = acc[m][0][r] + tb[0];
        float gf = acc[m][1][r] + tb[16];
        float gg = acc[m][2][r] + tb[32];
        float go = acc[m][3][r] + tb[48];
        float cold = (t > 0) ? (float)c0h[rowg * 256 + jh] : 0.f;
        float cn = sigm(gf) * cold + sigm(gi) * tanh_(gg);
        c0h[rowg * 256 + jh] = (_Float16)cn;
        ring0Cur[rowg * 256 + jh] = f2bf(sigm(go) * tanh_(cn));
      }
    }
  } else {
    const int bbb = ni * 128 + wn * 64 + l15;
    float b0 = bias1[bbb], b1 = bias1[bbb + 16], b2 = bias1[bbb + 32], b3 = bias1[bbb + 48];
#pragma unroll
    for (int m = 0; m < 5; ++m) {
#pragma unroll
      for (int r = 0; r < 4; ++r) {
        int rowg = rows + rw + m * 16 + lhi * 4 + r;
        float gi = acc[m][0][r] + b0;
        float gf = acc[m][1][r] + b1;
        float gg = acc[m][2][r] + b2;
        float go = acc[m][3][r] + b3;
        float cold = (t > 0) ? (float)c1h[rowg * 256 + jh] : 0.f;
        float cn = sigm(gf) * cold + sigm(gi) * tanh_(gg);
        c1h[rowg * 256 + jh] = (_Float16)cn;
        h1Cur[rowg * 256 + jh] = f2bf(sigm(go) * tanh_(cn));
      }
    }
  }
#undef LOADR
#undef STORER
#undef CONSUME
}

// ---------------- decoder ----------------
// out[64][100]; flat row r = h1 rows [r*80,(r+1)*80) = linear [r*20480,+20480).
// Block b (256 total): contiguous slice [b*5120, +5120) -> LDS (f32), 100 lanes
// dot vs row-contiguous dec_w, atomicAdd partials into zeroed out.
__global__ __launch_bounds__(128) void decoder_kernel(
    const unsigned short* __restrict__ h1, const float* __restrict__ dec_w,
    const float* __restrict__ dec_b, float* __restrict__ out) {
  __shared__ float hs[5120];
  const int tid = threadIdx.x;
  const int b = blockIdx.x;
  const int r = b >> 2;
  const int qoff = (b & 3) * 5120;

  const unsigned short* src = h1 + (size_t)b * 5120;
  for (int i = tid; i < 1280; i += 128) {
    u16x4 v = *(const u16x4*)(src + i * 4);
#pragma unroll
    for (int e = 0; e < 4; ++e) hs[i * 4 + e] = bf2f(v[e]);
  }
  __syncthreads();

  if (tid < NVOC) {
    const int v = tid;
    const f32x4* w4 = (const f32x4*)(dec_w + (size_t)v * 20480 + qoff);
    const f32x4* h4 = (const f32x4*)hs;
    float s = 0.f;
#pragma unroll 4
    for (int q = 0; q < 1280; ++q) {
      f32x4 a = h4[q], w = w4[q];
      s += a[0] * w[0] + a[1] * w[1] + a[2] * w[2] + a[3] * w[3];
    }
    if ((b & 3) == 0) s += dec_b[v];
    atomicAdd(&out[r * 100 + v], s);
  }
}

// ---------------- host launch: prep + 81 step kernels + decoder ----------------
extern "C" void kernel_launch(void* const* d_in, const int* in_sizes, int n_in,
                              void* d_out, int out_size, void* d_ws, size_t ws_size,
                              hipStream_t stream) {
  const int*   x     = (const int*)d_in[0];
  const float* emb   = (const float*)d_in[1];
  const float* w_ih0 = (const float*)d_in[2];
  const float* w_hh0 = (const float*)d_in[3];
  const float* b_ih0 = (const float*)d_in[4];
  const float* b_hh0 = (const float*)d_in[5];
  const float* w_ih1 = (const float*)d_in[6];
  const float* w_hh1 = (const float*)d_in[7];
  const float* b_ih1 = (const float*)d_in[8];
  const float* b_hh1 = (const float*)d_in[9];
  const float* dec_w = (const float*)d_in[10];
  const float* dec_b = (const float*)d_in[11];
  float* out = (float*)d_out;
  char* ws = (char*)d_ws;

  float*          table0 = (float*)(ws + OFF_TABLE0);
  float*          bias1  = (float*)(ws + OFF_BIAS1);
  unsigned short* Bpack  = (unsigned short*)(ws + OFF_BPACK);
  unsigned short* ring0  = (unsigned short*)(ws + OFF_RING0);
  unsigned short* ring1  = (unsigned short*)(ws + OFF_RING1);
  _Float16*       c0h    = (_Float16*)(ws + OFF_C0);
  _Float16*       c1h    = (_Float16*)(ws + OFF_C1);

  hipMemsetAsync(out, 0, (size_t)out_size * 4, stream);
  prep_kernel<<<3476, 256, 0, stream>>>(emb, w_ih0, w_hh0, b_ih0, b_hh0,
                                        w_ih1, w_hh1, b_ih1, b_hh1,
                                        table0, bias1, Bpack);
  hipFuncSetAttribute((const void*)step_kernel,
                      hipFuncAttributeMaxDynamicSharedMemorySize, SMEM_BYTES);
  for (int s = 0; s <= T_SEQ; ++s)
    step_kernel<<<256, 512, SMEM_BYTES, stream>>>(s, x, table0, bias1, Bpack,
                                                  ring0, ring1, c0h, c1h);
  decoder_kernel<<<256, 128, 0, stream>>>(ring1 + NBH, dec_w, dec_b, out);
}

// Round 11
// 1522.691 us; speedup vs baseline: 5.7450x; 1.3945x over previous
//
#include <hip/hip_runtime.h>

// ---------------- problem constants ----------------
#define T_SEQ 80
#define NB    5120
#define NBH   (NB * 256)
#define NVOC  100

// ---------------- ws layout (bytes), total ~17.7 MB ----------------
#define OFF_TABLE0 0u          // 100*1024*4 = 409600 (f32, np-packed)
#define OFF_BIAS1  409600u     // 1024*4     = 4096
#define OFF_BPACK  413696u     // 786432*2   = 1572864 (bf16 frag-layout weights)
#define OFF_RING0  1986560u    // 2 slots bf16 [5120][256] = 5242880
#define OFF_RING1  7229440u    // 2 slots bf16             = 5242880
#define OFF_C0     12472320u   // _Float16, c4 layout      = 2621440
#define OFF_C1     15093760u   // _Float16, c4 layout      = 2621440

// LDS: Ab 2x(160x80B)=25600 + Bb 2x8192=16384 + xs 640
#define SMEM_BYTES 42624

typedef float  f32x4  __attribute__((ext_vector_type(4)));
typedef __bf16 bf16x8 __attribute__((ext_vector_type(8)));
typedef short  s16x8  __attribute__((ext_vector_type(8)));
typedef _Float16 f16x4 __attribute__((ext_vector_type(4)));
typedef unsigned short u16x8 __attribute__((ext_vector_type(8)));

// column permutation: np -> original gate-major row (i,f,g,o blocks of 256)
__device__ __forceinline__ int colmap(int np) {
  int gate = (np >> 4) & 3;
  int j    = ((np >> 6) << 4) | (np & 15);
  return gate * 256 + j;
}

__device__ __forceinline__ unsigned short f2bf(float f) {
  unsigned int u = __float_as_uint(f);
  u += 0x7fffu + ((u >> 16) & 1u);   // RNE
  return (unsigned short)(u >> 16);
}
__device__ __forceinline__ float bf2f(unsigned short s) {
  return __uint_as_float(((unsigned int)s) << 16);
}
__device__ __forceinline__ float sigm(float x) {
  x = fminf(fmaxf(x, -20.f), 20.f);
  return 1.f / (1.f + __expf(-x));
}
__device__ __forceinline__ float tanh_(float x) {
  x = fminf(fmaxf(x, -10.f), 10.f);
  float e = __expf(2.f * x);
  return (e - 1.f) / (e + 1.f);
}

// ---------------- prep: table + bias + bf16 weight pack (same as R10) ----------------
__global__ void prep_kernel(const float* __restrict__ emb,
                            const float* __restrict__ w_ih0, const float* __restrict__ w_hh0,
                            const float* __restrict__ b_ih0, const float* __restrict__ b_hh0,
                            const float* __restrict__ w_ih1, const float* __restrict__ w_hh1,
                            const float* __restrict__ b_ih1, const float* __restrict__ b_hh1,
                            float* __restrict__ table0, float* __restrict__ bias1,
                            unsigned short* __restrict__ Bpack) {
  int idx = blockIdx.x * 256 + threadIdx.x;
  if (idx < 102400) {
    int v = idx >> 10, np = idx & 1023;
    int row = colmap(np);
    float s = b_ih0[row] + b_hh0[row];
#pragma unroll
    for (int e = 0; e < 8; ++e) s = fmaf(emb[v * 8 + e], w_ih0[row * 8 + e], s);
    table0[idx] = s;
  } else if (idx < 103424) {
    int np = idx - 102400;
    bias1[np] = b_ih1[colmap(np)] + b_hh1[colmap(np)];
  } else {
    int i2 = idx - 103424;               // < 786432
    int i    = i2 & 7;
    int t    = (i2 >> 3) & 511;
    int ni   = (i2 >> 12) & 7;
    int slot = i2 >> 15;                 // 0..23
    int np   = ni * 128 + ((t >> 6) << 4) + (t & 15);
    int row  = colmap(np);
    int k    = (((t & 63) >> 4) << 3) + i;
    float val;
    if (slot < 8) {
      val = w_hh0[row * 256 + slot * 32 + k];
    } else {
      int kc = slot - 8;
      const float* W = (kc < 8) ? w_ih1 : w_hh1;
      val = W[row * 256 + (kc & 7) * 32 + k];
    }
    Bpack[i2] = f2bf(val);
  }
}

// ---------------- per-step kernel ----------------
// Grid 512: p -> (xcd=p&7, idx=p>>3). idx<32: L0(t=s); else L1(t=s-1).
// Tile [160 x 128], 256 thr = 4 waves (2m x 2n), wave [80 x 64].
// mi = xcd*4 + (sub>>3): each XCD owns 4 complete mi row-groups per layer.
// c-state in c4 layout [row/4][256][4] f16 -> 8B per-thread vector access.
__global__ __launch_bounds__(256, 1) void step_kernel(
    int s, const int* __restrict__ x,
    const float* __restrict__ table0, const float* __restrict__ bias1,
    const unsigned short* __restrict__ Bpack,
    unsigned short* __restrict__ ring0, unsigned short* __restrict__ ring1,
    _Float16* __restrict__ c0h, _Float16* __restrict__ c1h) {
  extern __shared__ char smem[];
  char* Ab = smem;            // [2][160*80]
  char* Bb = smem + 25600;    // [2][512*16]
  int*  xs = (int*)(smem + 41984);   // [160]

  const int tid = threadIdx.x;
  const int lane = tid & 63, wid = tid >> 6;
  const int l15 = lane & 15, lhi = lane >> 4;
  const int wm = wid >> 1, wn = wid & 1, rw = wm * 80;

  const int p = blockIdx.x;
  const int xcd = p & 7, idx = p >> 3;
  const bool isL0 = idx < 32;
  const int sub = idx & 31;
  const int mi = xcd * 4 + (sub >> 3);
  const int ni = sub & 7;
  const int rows = mi * 160;

  int t;
  if (isL0) { if (s == T_SEQ) return; t = s; }
  else      { if (s == 0)     return; t = s - 1; }

  const unsigned short* ring0Prev = ring0 + ((s + 1) & 1) * NBH;  // h0(s-1)
  unsigned short*       ring0Cur  = ring0 + (s & 1) * NBH;        // h0(s)
  const unsigned short* h1Prev    = ring1 + (s & 1) * NBH;        // h1(s-2)
  unsigned short*       h1Cur     = ring1 + ((s + 1) & 1) * NBH;  // h1(s-1)

  const int KC = isL0 ? (t > 0 ? 8 : 0) : (t > 0 ? 16 : 8);

  // stage x tile (L0 only): coalesced, consumed by epilogue via LDS broadcast
  if (isL0 && tid < 160) xs[tid] = x[t * NB + rows + tid];

  f32x4 acc[5][4];
#pragma unroll
  for (int m = 0; m < 5; ++m)
#pragma unroll
    for (int nf = 0; nf < 4; ++nf) acc[m][nf] = (f32x4)0.f;

  uint4 au0, au1, au2;
  s16x8 bsr0, bsr1;

#define LOADR(kc_) do { \
    const unsigned short* _As; int _ko; \
    if (isL0) { _As = ring0Prev; _ko = (kc_) * 32; } \
    else { _As = ((kc_) < 8) ? ring0Prev : h1Prev; _ko = ((kc_) & 7) * 32; } \
    { int _c = tid;       au0 = *(const uint4*)(_As + (rows + (_c >> 2)) * 256 + _ko + ((_c & 3) << 3)); } \
    { int _c = tid + 256; au1 = *(const uint4*)(_As + (rows + (_c >> 2)) * 256 + _ko + ((_c & 3) << 3)); } \
    if (tid < 128) { int _c = tid + 512; au2 = *(const uint4*)(_As + (rows + (_c >> 2)) * 256 + _ko + ((_c & 3) << 3)); } \
    int _slot = isL0 ? (kc_) : (8 + (kc_)); \
    bsr0 = *(const s16x8*)(Bpack + (((_slot * 8 + ni) * 512 + tid) << 3)); \
    bsr1 = *(const s16x8*)(Bpack + (((_slot * 8 + ni) * 512 + tid + 256) << 3)); \
  } while (0)

#define STORER(buf_) do { \
    char* _ab = Ab + (buf_) * 12800; \
    *(uint4*)(_ab + (tid >> 2) * 80 + (tid & 3) * 16) = au0; \
    { int _c = tid + 256; *(uint4*)(_ab + (_c >> 2) * 80 + (_c & 3) * 16) = au1; } \
    if (tid < 128) { int _c = tid + 512; *(uint4*)(_ab + (_c >> 2) * 80 + (_c & 3) * 16) = au2; } \
    char* _bb = Bb + (buf_) * 8192; \
    *(s16x8*)(_bb + tid * 16) = bsr0; \
    *(s16x8*)(_bb + (tid + 256) * 16) = bsr1; \
  } while (0)

#define CONSUME(buf_) do { \
    const char* _ab = Ab + (buf_) * 12800; \
    const char* _bp = Bb + (buf_) * 8192; \
    bf16x8 _bld[4]; \
    _Pragma("unroll") \
    for (int _nf = 0; _nf < 4; ++_nf) \
      _bld[_nf] = *(const bf16x8*)(_bp + ((wn * 4 + _nf) * 64 + lane) * 16); \
    _Pragma("unroll") \
    for (int _m = 0; _m < 5; ++_m) { \
      bf16x8 _a = *(const bf16x8*)(_ab + (rw + _m * 16 + l15) * 80 + lhi * 16); \
      _Pragma("unroll") \
      for (int _nf = 0; _nf < 4; ++_nf) \
        acc[_m][_nf] = __builtin_amdgcn_mfma_f32_16x16x32_bf16(_a, _bld[_nf], acc[_m][_nf], 0, 0, 0); \
    } \
  } while (0)

  if (KC > 0) { LOADR(0); STORER(0); }
#pragma unroll 1
  for (int kc = 0; kc < KC; ++kc) {
    __syncthreads();                       // publishes buf[kc&1] (+ xs on kc==0)
    const bool more = (kc + 1 < KC);
    if (more) LOADR(kc + 1);               // issue early: hides under MFMAs
    CONSUME(kc & 1);
    if (more) STORER((kc + 1) & 1);        // write late (readers synced at top)
  }
  if (KC == 0) __syncthreads();            // publish xs (s==0 L0 path)

  // ---------------- epilogue: LSTM cell update ----------------
  const int jh = (ni * 2 + wn) * 16 + l15;          // h-column
  if (isL0) {
    const int tbb = ni * 128 + wn * 64 + l15;
#pragma unroll
    for (int m = 0; m < 5; ++m) {
      const int cbase = ((rows + rw + m * 16) >> 2) + lhi;   // c4 row-group
      f16x4 cold4 = (f16x4)(_Float16)0.f;
      if (t > 0) cold4 = *(const f16x4*)(c0h + cbase * 1024 + jh * 4);
      f16x4 cnew;
#pragma unroll
      for (int r = 0; r < 4; ++r) {
        int rowl = rw + m * 16 + lhi * 4 + r;
        const float* tb = table0 + xs[rowl] * 1024 + tbb;
        float gi = acc[m][0][r] + tb[0];
        float gf = acc[m][1][r] + tb[16];
        float gg = acc[m][2][r] + tb[32];
        float go = acc[m][3][r] + tb[48];
        float cn = sigm(gf) * (float)cold4[r] + sigm(gi) * tanh_(gg);
        cnew[r] = (_Float16)cn;
        ring0Cur[(rows + rowl) * 256 + jh] = f2bf(sigm(go) * tanh_(cn));
      }
      *(f16x4*)(c0h + cbase * 1024 + jh * 4) = cnew;
    }
  } else {
    const int bbb = ni * 128 + wn * 64 + l15;
    float b0 = bias1[bbb], b1 = bias1[bbb + 16], b2 = bias1[bbb + 32], b3 = bias1[bbb + 48];
#pragma unroll
    for (int m = 0; m < 5; ++m) {
      const int cbase = ((rows + rw + m * 16) >> 2) + lhi;
      f16x4 cold4 = (f16x4)(_Float16)0.f;
      if (t > 0) cold4 = *(const f16x4*)(c1h + cbase * 1024 + jh * 4);
      f16x4 cnew;
#pragma unroll
      for (int r = 0; r < 4; ++r) {
        int rowl = rw + m * 16 + lhi * 4 + r;
        float gi = acc[m][0][r] + b0;
        float gf = acc[m][1][r] + b1;
        float gg = acc[m][2][r] + b2;
        float go = acc[m][3][r] + b3;
        float cn = sigm(gf) * (float)cold4[r] + sigm(gi) * tanh_(gg);
        cnew[r] = (_Float16)cn;
        h1Cur[(rows + rowl) * 256 + jh] = f2bf(sigm(go) * tanh_(cn));
      }
      *(f16x4*)(c1h + cbase * 1024 + jh * 4) = cnew;
    }
  }
#undef LOADR
#undef STORER
#undef CONSUME
}

// ---------------- decoder: wave-per-v, fully coalesced dec_w streams ----------------
// 256 blocks: r = b>>2, qoff = (b&3)*5120. hs[5120] f32 in LDS.
// Wave w handles v = w, w+4, ...: lanes stride q by 4 floats -> 1KB/wave coalesced.
__global__ __launch_bounds__(256) void decoder_kernel(
    const unsigned short* __restrict__ h1, const float* __restrict__ dec_w,
    const float* __restrict__ dec_b, float* __restrict__ out) {
  __shared__ float hs[5120];
  const int tid = threadIdx.x, lane = tid & 63, wid = tid >> 6;
  const int b = blockIdx.x;
  const int r = b >> 2;
  const int qoff = (b & 3) * 5120;

  const unsigned short* src = h1 + (size_t)b * 5120;
  for (int i = tid; i < 640; i += 256) {
    u16x8 v8 = *(const u16x8*)(src + i * 8);
#pragma unroll
    for (int e = 0; e < 8; ++e) hs[i * 8 + e] = bf2f(v8[e]);
  }
  __syncthreads();

  for (int vv = wid; vv < NVOC; vv += 4) {
    const float* wp = dec_w + (size_t)vv * 20480 + qoff + lane * 4;
    const float* hp = hs + lane * 4;
    float s = 0.f;
#pragma unroll
    for (int it = 0; it < 20; ++it) {
      f32x4 w4 = *(const f32x4*)(wp + it * 256);
      f32x4 h4 = *(const f32x4*)(hp + it * 256);
      s += w4[0] * h4[0] + w4[1] * h4[1] + w4[2] * h4[2] + w4[3] * h4[3];
    }
#pragma unroll
    for (int off = 32; off > 0; off >>= 1) s += __shfl_down(s, off, 64);
    if (lane == 0) {
      if ((b & 3) == 0) s += dec_b[vv];
      atomicAdd(&out[r * 100 + vv], s);
    }
  }
}

// ---------------- host launch: prep + 81 step kernels + decoder ----------------
extern "C" void kernel_launch(void* const* d_in, const int* in_sizes, int n_in,
                              void* d_out, int out_size, void* d_ws, size_t ws_size,
                              hipStream_t stream) {
  const int*   x     = (const int*)d_in[0];
  const float* emb   = (const float*)d_in[1];
  const float* w_ih0 = (const float*)d_in[2];
  const float* w_hh0 = (const float*)d_in[3];
  const float* b_ih0 = (const float*)d_in[4];
  const float* b_hh0 = (const float*)d_in[5];
  const float* w_ih1 = (const float*)d_in[6];
  const float* w_hh1 = (const float*)d_in[7];
  const float* b_ih1 = (const float*)d_in[8];
  const float* b_hh1 = (const float*)d_in[9];
  const float* dec_w = (const float*)d_in[10];
  const float* dec_b = (const float*)d_in[11];
  float* out = (float*)d_out;
  char* ws = (char*)d_ws;

  float*          table0 = (float*)(ws + OFF_TABLE0);
  float*          bias1  = (float*)(ws + OFF_BIAS1);
  unsigned short* Bpack  = (unsigned short*)(ws + OFF_BPACK);
  unsigned short* ring0  = (unsigned short*)(ws + OFF_RING0);
  unsigned short* ring1  = (unsigned short*)(ws + OFF_RING1);
  _Float16*       c0h    = (_Float16*)(ws + OFF_C0);
  _Float16*       c1h    = (_Float16*)(ws + OFF_C1);

  hipMemsetAsync(out, 0, (size_t)out_size * 4, stream);
  prep_kernel<<<3476, 256, 0, stream>>>(emb, w_ih0, w_hh0, b_ih0, b_hh0,
                                        w_ih1, w_hh1, b_ih1, b_hh1,
                                        table0, bias1, Bpack);
  hipFuncSetAttribute((const void*)step_kernel,
                      hipFuncAttributeMaxDynamicSharedMemorySize, SMEM_BYTES);
  for (int s = 0; s <= T_SEQ; ++s)
    step_kernel<<<512, 256, SMEM_BYTES, stream>>>(s, x, table0, bias1, Bpack,
                                                  ring0, ring1, c0h, c1h);
  decoder_kernel<<<256, 256, 0, stream>>>(ring1 + NBH, dec_w, dec_b, out);
}